// Round 2
// baseline (172.464 us; speedup 1.0000x reference)
//
#include <hip/hip_runtime.h>

#define VOCAB 50000
#define EMBED 256
#define NB    16
#define NC    64
#define NS    512
#define UNK   1

// ---- bf16 fast path geometry (R9 = R7 geometry + SW-pipelined gathers) ----
// R8 post-mortem: JLEN=16 + per-iter global query loads halved effective gather
// BW (8.6 -> 4.4 TB/s) at unchanged occupancy -> kernel is latency/ILP-bound,
// not occupancy-bound. Revert to R7 (CTILE=16, JT=16, JLEN=32, f32 qt in LDS,
// full-row uint2 gathers) and add depth-1 prefetch of the 16 gather rows.
#define CTILE 16              // c's per block
#define JT    16              // j tiles
#define JLEN  (NS / JT)       // 32 j's per tile
#define BF_TABLE_BYTES ((size_t)VOCAB * EMBED * 2)          // 25,600,000
#define PARTIAL_ELEMS  (JT * NB * NC)                       // 16384

__device__ __forceinline__ unsigned short f2bf_rne(float f) {
    unsigned int u = __float_as_uint(f);
    u = (u + 0x7fffu + ((u >> 16) & 1u)) >> 16;             // round-nearest-even
    return (unsigned short)u;
}

// Stream-convert emb f32 -> bf16 table in ws. 400k threads x 8 elems.
__global__ __launch_bounds__(256) void convert_kernel(
    const float* __restrict__ emb, unsigned int* __restrict__ bf)
{
    const size_t t = (size_t)blockIdx.x * 256 + threadIdx.x;
    const float4* __restrict__ e4 = (const float4*)emb;
    const float4 a = e4[t * 2];
    const float4 b = e4[t * 2 + 1];
    uint4 r;
    r.x = (unsigned int)f2bf_rne(a.x) | ((unsigned int)f2bf_rne(a.y) << 16);
    r.y = (unsigned int)f2bf_rne(a.z) | ((unsigned int)f2bf_rne(a.w) << 16);
    r.z = (unsigned int)f2bf_rne(b.x) | ((unsigned int)f2bf_rne(b.y) << 16);
    r.w = (unsigned int)f2bf_rne(b.z) | ((unsigned int)f2bf_rne(b.w) << 16);
    ((uint4*)bf)[t] = r;
}

// Gather-bound scores, bf16 source rows (512 B each), f32 query rows staged
// in LDS once per block. Grid = NB * (NC/CTILE) * JT = 1024 blocks, 256 thr.
// Depth-1 software pipeline: gathers for stage it+1 are issued before stage
// it's FMAs consume the previous buffer -> each wave keeps ~32 row-gathers
// in flight instead of 16, hiding L2/L3 latency (~200-600 cy).
__global__ __launch_bounds__(256, 4) void scores_bf_kernel(
    const int* __restrict__ src, const int* __restrict__ q,
    const float* __restrict__ emb, const unsigned int* __restrict__ bf,
    float* __restrict__ partial)
{
    const int x  = blockIdx.x;
    const int jt = x & (JT - 1);
    const int ct = (x >> 4) & (NC / CTILE - 1);
    const int b  = x >> 6;
    const int c0 = ct * CTILE;
    const int j0 = jt * JLEN;

    const int tid  = threadIdx.x;
    const int wave = tid >> 6;
    const int lane = tid & 63;          // covers elements [4*lane, 4*lane+3]

    const float4* __restrict__ emb4 = (const float4*)emb;
    const uint2*  __restrict__ bfe  = (const uint2*)bf;       // 64 uint2 per row
    const int* __restrict__ qrow = q + (size_t)b * NS;
    const int* __restrict__ srow = src + ((size_t)b * NC + c0) * NS;

    __shared__ float qt[JLEN][EMBED];   // 32 KB: query rows for this j tile, f32
    __shared__ int   sids[CTILE][JLEN]; // 2 KB clamped source ids
    __shared__ int   qids[JLEN];
    __shared__ int   nnz_sh;

    if (tid < 64) {                                  // wave 0
        const int qv = (tid < JLEN) ? qrow[j0 + tid] : 0;
        if (tid < JLEN) qids[tid] = (qv >= VOCAB) ? UNK : qv;
        const unsigned long long bal = __ballot(qv > 0);
        if (tid == 0) nnz_sh = __popcll(bal);        // contiguous prefix in tile
    }
    // 512 tile ids, 2 per thread, coalesced
#pragma unroll
    for (int k = 0; k < 2; k++) {
        const int idx = tid + k * 256;
        const int i   = idx >> 5;       // c within tile (0..15)
        const int j   = idx & 31;
        const int sv  = srow[(size_t)i * NS + j0 + j];
        sids[i][j] = (sv >= VOCAB) ? UNK : sv;
    }
    __syncthreads();

    const int nnz = nnz_sh;

    // stage f32 query rows for valid j's (wave w -> rows w, w+4, ...)
    float4* qt4 = (float4*)qt;
    for (int r = wave; r < nnz; r += 4)
        qt4[r * 64 + lane] = emb4[(size_t)qids[r] * (EMBED / 4) + lane];
    __syncthreads();

    float acc[CTILE];
#pragma unroll
    for (int i = 0; i < CTILE; i++) acc[i] = 0.f;

    // ---- depth-1 pipelined gather loop (8 static stages, wave-uniform exits) ----
    uint2 aA[CTILE], aB[CTILE];
    if (wave < nnz) {
#pragma unroll
        for (int i = 0; i < CTILE; i++)
            aA[i] = bfe[(size_t)sids[i][wave] * 64 + lane];
    }
#pragma unroll
    for (int it = 0; it < 8; ++it) {
        const int j = wave + it * 4;
        if (j >= nnz) break;            // nnz block-uniform, j wave-uniform
        const int jn = j + 4;
        if (jn < nnz) {                 // prefetch next stage into the other buffer
            if ((it & 1) == 0) {
#pragma unroll
                for (int i = 0; i < CTILE; i++)
                    aB[i] = bfe[(size_t)sids[i][jn] * 64 + lane];
            } else {
#pragma unroll
                for (int i = 0; i < CTILE; i++)
                    aA[i] = bfe[(size_t)sids[i][jn] * 64 + lane];
            }
        }
        const float4 qv = qt4[j * 64 + lane];        // ds_read_b128
        if ((it & 1) == 0) {
#pragma unroll
            for (int i = 0; i < CTILE; i++) {
                const float f0 = __uint_as_float(aA[i].x << 16);
                const float f1 = __uint_as_float(aA[i].x & 0xffff0000u);
                const float f2 = __uint_as_float(aA[i].y << 16);
                const float f3 = __uint_as_float(aA[i].y & 0xffff0000u);
                acc[i] += f0 * qv.x + f1 * qv.y + f2 * qv.z + f3 * qv.w;
            }
        } else {
#pragma unroll
            for (int i = 0; i < CTILE; i++) {
                const float f0 = __uint_as_float(aB[i].x << 16);
                const float f1 = __uint_as_float(aB[i].x & 0xffff0000u);
                const float f2 = __uint_as_float(aB[i].y << 16);
                const float f3 = __uint_as_float(aB[i].y & 0xffff0000u);
                acc[i] += f0 * qv.x + f1 * qv.y + f2 * qv.z + f3 * qv.w;
            }
        }
    }

#pragma unroll
    for (int off = 32; off > 0; off >>= 1)
#pragma unroll
        for (int i = 0; i < CTILE; i++)
            acc[i] += __shfl_down(acc[i], off, 64);

    __shared__ float red[4][CTILE];
    if (lane == 0)
#pragma unroll
        for (int i = 0; i < CTILE; i++) red[wave][i] = acc[i];
    __syncthreads();

    if (tid < CTILE) {
        const float s = red[0][tid] + red[1][tid] + red[2][tid] + red[3][tid];
        partial[(size_t)jt * (NB * NC) + b * NC + c0 + tid] = s;
    }
}

// ---- f32 fallback (proven R5 path), JT=8/JLEN=64, CTILE=8 ----
__global__ __launch_bounds__(256) void scores_f32_kernel(
    const int* __restrict__ src, const int* __restrict__ q,
    const float* __restrict__ emb, float* __restrict__ partial)
{
    const int x  = blockIdx.x;
    const int jt = x & 7;
    const int ct = (x >> 3) & 7;
    const int b  = x >> 6;
    const int c0 = ct * 8;
    const int j0 = jt * 64;

    const int tid = threadIdx.x, wave = tid >> 6, lane = tid & 63;
    const float4* __restrict__ emb4 = (const float4*)emb;
    const int* __restrict__ qrow = q + (size_t)b * NS;
    const int* __restrict__ srow = src + ((size_t)b * NC + c0) * NS;

    float acc[8];
#pragma unroll
    for (int i = 0; i < 8; i++) acc[i] = 0.f;

    for (int j = j0 + wave; j < j0 + 64; j += 4) {
        const int qv = qrow[j];
        if (qv > 0) {
            const int qid = (qv >= VOCAB) ? UNK : qv;
            const float4 eq = emb4[(size_t)qid * (EMBED / 4) + lane];
            float4 a[8];
#pragma unroll
            for (int i = 0; i < 8; i++) {
                const int sv = srow[(size_t)i * NS + j];
                a[i] = emb4[(size_t)((sv >= VOCAB) ? UNK : sv) * (EMBED / 4) + lane];
            }
#pragma unroll
            for (int i = 0; i < 8; i++)
                acc[i] += a[i].x * eq.x + a[i].y * eq.y + a[i].z * eq.z + a[i].w * eq.w;
        }
    }
#pragma unroll
    for (int off = 32; off > 0; off >>= 1)
#pragma unroll
        for (int i = 0; i < 8; i++)
            acc[i] += __shfl_down(acc[i], off, 64);

    __shared__ float red[4][8];
    if (lane == 0)
#pragma unroll
        for (int i = 0; i < 8; i++) red[wave][i] = acc[i];
    __syncthreads();
    if (tid < 8)
        partial[(size_t)jt * (NB * NC) + b * NC + c0 + tid] =
            red[0][tid] + red[1][tid] + red[2][tid] + red[3][tid];
}

// One block per b. Wave 0: sum jtn partials -> softmax -> sims + argmax;
// then all 256 threads copy the winning source row as f32.
__global__ __launch_bounds__(256) void finalize_kernel(
    const float* __restrict__ partial, const int* __restrict__ src,
    float* __restrict__ out, int jtn)
{
    const int b = blockIdx.x, tid = threadIdx.x;
    __shared__ int top_sh;

    if (tid < 64) {
        float s = 0.f;
        for (int t = 0; t < jtn; t++)
            s += partial[(size_t)t * (NB * NC) + b * NC + tid];

        float m = s;
#pragma unroll
        for (int off = 32; off > 0; off >>= 1)
            m = fmaxf(m, __shfl_xor(m, off, 64));
        const float e = expf(s - m);
        float sum = e;
#pragma unroll
        for (int off = 32; off > 0; off >>= 1)
            sum += __shfl_xor(sum, off, 64);

        out[NB * NS + b * NC + tid] = e / sum;       // sims after 8192 ids

        const unsigned long long ballot = __ballot(s == m);
        if (tid == 0) top_sh = __ffsll(ballot) - 1;  // first occurrence
    }
    __syncthreads();

    const int top = top_sh;
    const int* __restrict__ srow = src + ((size_t)b * NC + top) * NS;
    for (int j = tid; j < NS; j += 256)
        out[b * NS + j] = (float)srow[j];
}

extern "C" void kernel_launch(void* const* d_in, const int* in_sizes, int n_in,
                              void* d_out, int out_size, void* d_ws, size_t ws_size,
                              hipStream_t stream) {
    const int*   src = (const int*)d_in[0];    // [NB*NC, NS] int32
    const int*   q   = (const int*)d_in[1];    // [NB, NS] int32
    const float* emb = (const float*)d_in[3];  // [VOCAB, EMBED] f32
    float* out = (float*)d_out;                // 8192 out_sources + 1024 sims (f32)

    if (ws_size >= BF_TABLE_BYTES + PARTIAL_ELEMS * sizeof(float)) {
        unsigned int* bf = (unsigned int*)d_ws;
        float* partial = (float*)((char*)d_ws + BF_TABLE_BYTES);
        convert_kernel<<<VOCAB * EMBED / 2048, 256, 0, stream>>>(emb, bf);
        scores_bf_kernel<<<NB * (NC / CTILE) * JT, 256, 0, stream>>>(src, q, emb, bf, partial);
        finalize_kernel<<<NB, 256, 0, stream>>>(partial, src, out, JT);
    } else {
        float* partial = (float*)d_ws;         // 8192 floats
        scores_f32_kernel<<<NB * 8 * 8, 256, 0, stream>>>(src, q, emb, partial);
        finalize_kernel<<<NB, 256, 0, stream>>>(partial, src, out, 8);
    }
}

// Round 3
// 149.266 us; speedup vs baseline: 1.1554x; 1.1554x over previous
//
#include <hip/hip_runtime.h>

#define VOCAB 50000
#define EMBED 256
#define NB    16
#define NC    64
#define NS    512
#define UNK   1

// ---- bf16 fast path (R10): XCD-partitioned gathers ----
// R8/R9 post-mortem: register double-buffer pipelining spilled to scratch
// (WRITE_SIZE 84/127 MB, VGPR capped) -> regressions. Root bottleneck per
// counters: 141 MB of the 268 MB gather stream misses L2 (table 25.6 MB >
// 4 MB/XCD) and is served by L3 at ~4.5 TB/s.
// R10: partition vocab into 8 slices of 6250 rows (3.2 MB, fits one XCD L2).
// Grid = b x jt x partition with partition = blockIdx%8 -> XCD round-robin,
// so each XCD's L2 retains exactly its slice; gathers become ~L2-resident.
#define NPART 8
#define PDIV  ((VOCAB + NPART - 1) / NPART)   // 6250 rows per partition
#define PJT   8                               // j tiles
#define PJLEN 64                              // j's per tile
#define WLCAP 1024                            // worklist capacity (mean 512, sigma 21)
#define NSLICE (NPART * PJT)                  // 64 partial slices
#define BF_TABLE_BYTES ((size_t)VOCAB * EMBED * 2)          // 25,600,000
#define PARTIAL_ELEMS  (NSLICE * NB * NC)                   // 65536

__device__ __forceinline__ unsigned short f2bf_rne(float f) {
    unsigned int u = __float_as_uint(f);
    u = (u + 0x7fffu + ((u >> 16) & 1u)) >> 16;             // round-nearest-even
    return (unsigned short)u;
}

// Stream-convert emb f32 -> bf16 table in ws. 400k threads x 8 elems.
__global__ __launch_bounds__(256) void convert_kernel(
    const float* __restrict__ emb, unsigned int* __restrict__ bf)
{
    const size_t t = (size_t)blockIdx.x * 256 + threadIdx.x;
    const float4* __restrict__ e4 = (const float4*)emb;
    const float4 a = e4[t * 2];
    const float4 b = e4[t * 2 + 1];
    uint4 r;
    r.x = (unsigned int)f2bf_rne(a.x) | ((unsigned int)f2bf_rne(a.y) << 16);
    r.y = (unsigned int)f2bf_rne(a.z) | ((unsigned int)f2bf_rne(a.w) << 16);
    r.z = (unsigned int)f2bf_rne(b.x) | ((unsigned int)f2bf_rne(b.y) << 16);
    r.w = (unsigned int)f2bf_rne(b.z) | ((unsigned int)f2bf_rne(b.w) << 16);
    ((uint4*)bf)[t] = r;
}

__device__ __forceinline__ float dot_u(unsigned a, unsigned b) {
    const float a0 = __uint_as_float(a << 16);
    const float a1 = __uint_as_float(a & 0xffff0000u);
    const float b0 = __uint_as_float(b << 16);
    const float b1 = __uint_as_float(b & 0xffff0000u);
    return a0 * b0 + a1 * b1;
}

// Grid = NB * PJT * NPART = 1024 blocks, 256 threads.
// Block (b, jt, p): filter the tile's 4096 ids to those in vocab partition p,
// gather only those rows (XCD-local L2 after warmup), accumulate per-c scores
// via LDS float atomics. Half-wave (32 lanes, uint4/lane) per row.
__global__ __launch_bounds__(256) void scores_part_kernel(
    const int* __restrict__ src, const int* __restrict__ q,
    const unsigned int* __restrict__ bf, float* __restrict__ partial)
{
    const int bid = blockIdx.x;
    const int p   = bid & (NPART - 1);          // -> XCD p (round-robin dispatch)
    const int jt  = (bid >> 3) & (PJT - 1);
    const int b   = bid >> 6;
    const int j0  = jt * PJLEN;

    const int tid  = threadIdx.x;
    const int wave = tid >> 6;
    const int lane = tid & 63;
    const int half = lane >> 5;                 // which entry this half serves
    const int hl   = lane & 31;                 // covers row bytes [16*hl,16*hl+16)

    const uint2* __restrict__ bfe  = (const uint2*)bf;      // 64 per row
    const uint4* __restrict__ bft4 = (const uint4*)bf;      // 32 per row

    __shared__ uint2 qt[PJLEN][64];             // bf16 q rows: 64 x 512 B = 32 KB
    __shared__ unsigned int wl[WLCAP];          // 4 KB packed (sid<<12)|(c<<6)|jj
    __shared__ float score_sh[NC];              // 256 B
    __shared__ int qid_sh[PJLEN];
    __shared__ int cnt;

    if (tid < PJLEN) {
        const int qv = q[(size_t)b * NS + j0 + tid];
        qid_sh[tid] = (qv == 0) ? -1 : ((qv >= VOCAB) ? UNK : qv);
    }
    if (tid < NC) score_sh[tid] = 0.f;
    if (tid == 0) cnt = 0;
    __syncthreads();

    // stage q rows (bf16) for valid j's; wave w -> rows w, w+4, ...
    for (int r = wave; r < PJLEN; r += 4) {
        const int qid = qid_sh[r];
        if (qid >= 0)
            qt[r][lane] = bfe[(size_t)qid * 64 + lane];
    }

    // filter 4096 tile ids -> worklist of this partition's entries
    const int* __restrict__ srow = src + (size_t)b * NC * NS;
#pragma unroll
    for (int k = 0; k < 16; k++) {
        const int idx = k * 256 + tid;          // = c*64 + jj
        const int c   = idx >> 6;
        const int jj  = idx & 63;
        int sv = srow[(size_t)c * NS + j0 + jj];
        sv = (sv >= VOCAB) ? UNK : sv;
        if (qid_sh[jj] >= 0 && (sv / PDIV) == p) {
            const int pos = atomicAdd(&cnt, 1);
            if (pos < WLCAP)
                wl[pos] = ((unsigned)sv << 12) | (unsigned)(c << 6) | (unsigned)jj;
        }
    }
    __syncthreads();

    const int nE = (cnt < WLCAP) ? cnt : WLCAP;

    // entry loop: 4 entries in flight per wave (2 halves x 2-deep unroll)
    for (int e = wave * 2; e < nE; e += 16) {
        const int eA = e + half;
        const int eB = e + 8 + half;
        const bool vA = eA < nE;
        const bool vB = eB < nE;
        const unsigned wA = wl[vA ? eA : 0];
        const unsigned wB = wl[vB ? eB : 0];
        const int sidA = wA >> 12, cA = (wA >> 6) & 63, jA = wA & 63;
        const int sidB = wB >> 12, cB = (wB >> 6) & 63, jB = wB & 63;
        const uint4 gA = bft4[(size_t)sidA * 32 + hl];
        const uint4 gB = bft4[(size_t)sidB * 32 + hl];
        const uint4 qA = ((const uint4*)qt[jA])[hl];
        const uint4 qB = ((const uint4*)qt[jB])[hl];
        float dA = dot_u(gA.x, qA.x) + dot_u(gA.y, qA.y)
                 + dot_u(gA.z, qA.z) + dot_u(gA.w, qA.w);
        float dB = dot_u(gB.x, qB.x) + dot_u(gB.y, qB.y)
                 + dot_u(gB.z, qB.z) + dot_u(gB.w, qB.w);
#pragma unroll
        for (int off = 16; off > 0; off >>= 1) {            // both halves at once
            dA += __shfl_down(dA, off, 32);
            dB += __shfl_down(dB, off, 32);
        }
        if (hl == 0) {
            if (vA) atomicAdd(&score_sh[cA], dA);
            if (vB) atomicAdd(&score_sh[cB], dB);
        }
    }
    __syncthreads();

    if (tid < NC)
        partial[(size_t)(p * PJT + jt) * (NB * NC) + b * NC + tid] = score_sh[tid];
}

// ---- f32 fallback (proven R5 path), JT=8/JLEN=64, CTILE=8 ----
__global__ __launch_bounds__(256) void scores_f32_kernel(
    const int* __restrict__ src, const int* __restrict__ q,
    const float* __restrict__ emb, float* __restrict__ partial)
{
    const int x  = blockIdx.x;
    const int jt = x & 7;
    const int ct = (x >> 3) & 7;
    const int b  = x >> 6;
    const int c0 = ct * 8;
    const int j0 = jt * 64;

    const int tid = threadIdx.x, wave = tid >> 6, lane = tid & 63;
    const float4* __restrict__ emb4 = (const float4*)emb;
    const int* __restrict__ qrow = q + (size_t)b * NS;
    const int* __restrict__ srow = src + ((size_t)b * NC + c0) * NS;

    float acc[8];
#pragma unroll
    for (int i = 0; i < 8; i++) acc[i] = 0.f;

    for (int j = j0 + wave; j < j0 + 64; j += 4) {
        const int qv = qrow[j];
        if (qv > 0) {
            const int qid = (qv >= VOCAB) ? UNK : qv;
            const float4 eq = emb4[(size_t)qid * (EMBED / 4) + lane];
            float4 a[8];
#pragma unroll
            for (int i = 0; i < 8; i++) {
                const int sv = srow[(size_t)i * NS + j];
                a[i] = emb4[(size_t)((sv >= VOCAB) ? UNK : sv) * (EMBED / 4) + lane];
            }
#pragma unroll
            for (int i = 0; i < 8; i++)
                acc[i] += a[i].x * eq.x + a[i].y * eq.y + a[i].z * eq.z + a[i].w * eq.w;
        }
    }
#pragma unroll
    for (int off = 32; off > 0; off >>= 1)
#pragma unroll
        for (int i = 0; i < 8; i++)
            acc[i] += __shfl_down(acc[i], off, 64);

    __shared__ float red[4][8];
    if (lane == 0)
#pragma unroll
        for (int i = 0; i < 8; i++) red[wave][i] = acc[i];
    __syncthreads();
    if (tid < 8)
        partial[(size_t)jt * (NB * NC) + b * NC + c0 + tid] =
            red[0][tid] + red[1][tid] + red[2][tid] + red[3][tid];
}

// One block per b. Wave 0: sum jtn partials -> softmax -> sims + argmax;
// then all 256 threads copy the winning source row as f32.
__global__ __launch_bounds__(256) void finalize_kernel(
    const float* __restrict__ partial, const int* __restrict__ src,
    float* __restrict__ out, int jtn)
{
    const int b = blockIdx.x, tid = threadIdx.x;
    __shared__ int top_sh;

    if (tid < 64) {
        float s = 0.f;
        for (int t = 0; t < jtn; t++)
            s += partial[(size_t)t * (NB * NC) + b * NC + tid];

        float m = s;
#pragma unroll
        for (int off = 32; off > 0; off >>= 1)
            m = fmaxf(m, __shfl_xor(m, off, 64));
        const float e = expf(s - m);
        float sum = e;
#pragma unroll
        for (int off = 32; off > 0; off >>= 1)
            sum += __shfl_xor(sum, off, 64);

        out[NB * NS + b * NC + tid] = e / sum;       // sims after 8192 ids

        const unsigned long long ballot = __ballot(s == m);
        if (tid == 0) top_sh = __ffsll(ballot) - 1;  // first occurrence
    }
    __syncthreads();

    const int top = top_sh;
    const int* __restrict__ srow = src + ((size_t)b * NC + top) * NS;
    for (int j = tid; j < NS; j += 256)
        out[b * NS + j] = (float)srow[j];
}

extern "C" void kernel_launch(void* const* d_in, const int* in_sizes, int n_in,
                              void* d_out, int out_size, void* d_ws, size_t ws_size,
                              hipStream_t stream) {
    const int*   src = (const int*)d_in[0];    // [NB*NC, NS] int32
    const int*   q   = (const int*)d_in[1];    // [NB, NS] int32
    const float* emb = (const float*)d_in[3];  // [VOCAB, EMBED] f32
    float* out = (float*)d_out;                // 8192 out_sources + 1024 sims (f32)

    if (ws_size >= BF_TABLE_BYTES + PARTIAL_ELEMS * sizeof(float)) {
        unsigned int* bf = (unsigned int*)d_ws;
        float* partial = (float*)((char*)d_ws + BF_TABLE_BYTES);
        convert_kernel<<<VOCAB * EMBED / 2048, 256, 0, stream>>>(emb, bf);
        scores_part_kernel<<<NB * PJT * NPART, 256, 0, stream>>>(src, q, bf, partial);
        finalize_kernel<<<NB, 256, 0, stream>>>(partial, src, out, NSLICE);
    } else {
        float* partial = (float*)d_ws;         // 8192 floats
        scores_f32_kernel<<<NB * 8 * 8, 256, 0, stream>>>(src, q, emb, partial);
        finalize_kernel<<<NB, 256, 0, stream>>>(partial, src, out, 8);
    }
}